// Round 2
// baseline (31798.337 us; speedup 1.0000x reference)
//
#include <hip/hip_runtime.h>
#include <hip/hip_bf16.h>

typedef __hip_bfloat16 bf16;
using short8 = __attribute__((ext_vector_type(8))) short;   // 8 bf16 (4 VGPRs) MFMA A/B frag
using f32x4  = __attribute__((ext_vector_type(4))) float;   // MFMA C/D frag

#define T_STEPS 2048
#define NBATCH  32
#define IDIM    256
#define HDIM    512
#define NB0     32          // layer-0 blocks (each owns 16 hidden units)
#define NB1     32          // layer-1 blocks
#define NBLK    (NB0 + NB1)
#define HBUF    (NBATCH * HDIM)   // one h buffer: 32 x 512 bf16

__device__ __forceinline__ float sigm(float x) { return 1.0f / (1.0f + __expf(-x)); }
__device__ __forceinline__ float tanh_f(float x) {
  x = fminf(fmaxf(x, -15.f), 15.f);
  float e = __expf(2.f * x);
  return (e - 1.f) / (e + 1.f);
}

__device__ __forceinline__ short bfbits(float f) {
  bf16 b = __float2bfloat16(f);
  short s;
  __builtin_memcpy(&s, &b, 2);
  return s;
}

// Convert 8 consecutive f32 -> bf16 MFMA fragment (two float4 loads, RNE converts).
__device__ __forceinline__ short8 cvt8(const float* __restrict__ p) {
  float4 lo = *(const float4*)(const void*)p;
  float4 hi = *(const float4*)(const void*)(p + 4);
  short8 r;
  r[0] = bfbits(lo.x); r[1] = bfbits(lo.y); r[2] = bfbits(lo.z); r[3] = bfbits(lo.w);
  r[4] = bfbits(hi.x); r[5] = bfbits(hi.y); r[6] = bfbits(hi.z); r[7] = bfbits(hi.w);
  return r;
}

// Device-scope grid barrier: monotonic counter, one arrival per block.
__device__ __forceinline__ void gbar(unsigned* cnt, unsigned target) {
  __syncthreads();              // all block waves' stores issued+complete
  if (threadIdx.x == 0) {
    __threadfence();            // device-scope release
    atomicAdd(cnt, 1u);         // device-scope by default on CDNA
    while (__hip_atomic_load(cnt, __ATOMIC_RELAXED, __HIP_MEMORY_SCOPE_AGENT) < target) {
      __builtin_amdgcn_s_sleep(1);
    }
    __threadfence();            // device-scope acquire
  }
  __syncthreads();
}

// One persistent kernel. Blocks [0,NB0): layer 0. Blocks [NB0,NBLK): layer 1 (lagged 1 step).
// Per block: 4 waves x 4 hidden units each. Gate rows packed per-unit [i,f,g,o] so the
// 16x16x32 MFMA D layout (row = 4*quad + reg, col = lane&15 = batch) puts one unit's
// four gates in one lane's 4 regs -> in-lane activations + register-resident cell state.
__global__ void __launch_bounds__(256, 1) lstm_persistent(
    const float* __restrict__ x,
    const float* __restrict__ Wih0, const float* __restrict__ Whh0,
    const float* __restrict__ bih0, const float* __restrict__ bhh0,
    const float* __restrict__ Wih1, const float* __restrict__ Whh1,
    const float* __restrict__ bih1, const float* __restrict__ bhh1,
    const float* __restrict__ fcw, const float* __restrict__ fcb,
    float* __restrict__ out,
    unsigned* __restrict__ cnt,
    bf16* __restrict__ h0buf, bf16* __restrict__ h1buf) {
  const int tid  = threadIdx.x;
  const int w    = tid >> 6;        // wave id 0..3
  const int lane = tid & 63;
  const int q    = lane >> 4;       // quad 0..3
  const int m    = lane & 15;       // A-frag row / B-frag col (batch) / D col (batch)
  const int q8   = q * 8;           // k offset within 32-wide k-chunk
  const bool is_l0 = (blockIdx.x < NB0);
  const int blk  = is_l0 ? (int)blockIdx.x : (int)blockIdx.x - NB0;
  const int jb   = blk * 16 + w * 4;        // wave's first hidden unit
  const int unit = jb + (m >> 2);           // A row m -> unit
  const int gate = m & 3;                   // A row m -> gate (i,f,g,o)
  const int wrow = gate * HDIM + unit;      // row in [4H, K] weight matrices
  const int ju   = jb + q;                  // D rows 4q..4q+3 -> unit ju, gates 0..3

  // ---- Preload all A-fragments (weights, f32 -> bf16) into VGPRs; constant across steps ----
  short8 A[32];
  f32x4 bias;
  if (is_l0) {
#pragma unroll
    for (int kc = 0; kc < 8; kc++)
      A[kc] = cvt8(Wih0 + wrow * IDIM + kc * 32 + q8);
#pragma unroll
    for (int kc = 0; kc < 16; kc++)
      A[8 + kc] = cvt8(Whh0 + wrow * HDIM + kc * 32 + q8);
#pragma unroll
    for (int r = 0; r < 4; r++)
      bias[r] = bih0[r * HDIM + ju] + bhh0[r * HDIM + ju];
  } else {
#pragma unroll
    for (int kc = 0; kc < 16; kc++)
      A[kc] = cvt8(Wih1 + wrow * HDIM + kc * 32 + q8);
#pragma unroll
    for (int kc = 0; kc < 16; kc++)
      A[16 + kc] = cvt8(Whh1 + wrow * HDIM + kc * 32 + q8);
#pragma unroll
    for (int r = 0; r < 4; r++)
      bias[r] = bih1[r * HDIM + ju] + bhh1[r * HDIM + ju];
  }

  float c_a = 0.f, c_b = 0.f;   // cell state: (unit ju, batch m) and (unit ju, batch m+16)

  for (int p = 0; p <= T_STEPS; ++p) {
    if (is_l0) {
      if (p < T_STEPS) {
        // h0[p] = cell0(x[p], h0[p-1])
        f32x4 a0 = bias, a1 = bias;
        const float* xa = x + (size_t)m * (T_STEPS * IDIM) + (size_t)p * IDIM + q8;
        const float* xb = xa + (size_t)16 * (T_STEPS * IDIM);
#pragma unroll
        for (int kc = 0; kc < 8; kc++) {
          short8 b0 = cvt8(xa + kc * 32);
          short8 b1 = cvt8(xb + kc * 32);
          a0 = __builtin_amdgcn_mfma_f32_16x16x32_bf16(A[kc], b0, a0, 0, 0, 0);
          a1 = __builtin_amdgcn_mfma_f32_16x16x32_bf16(A[kc], b1, a1, 0, 0, 0);
        }
        if (p > 0) {
          const bf16* hp = h0buf + ((p + 1) & 1) * HBUF;   // h0[p-1]
          const bf16* ha = hp + m * HDIM + q8;
          const bf16* hb = hp + (m + 16) * HDIM + q8;
#pragma unroll
          for (int kc = 0; kc < 16; kc++) {
            short8 b0 = *(const short8*)(const void*)(ha + kc * 32);
            short8 b1 = *(const short8*)(const void*)(hb + kc * 32);
            a0 = __builtin_amdgcn_mfma_f32_16x16x32_bf16(A[8 + kc], b0, a0, 0, 0, 0);
            a1 = __builtin_amdgcn_mfma_f32_16x16x32_bf16(A[8 + kc], b1, a1, 0, 0, 0);
          }
        }
        float ia = sigm(a0[0]), fa = sigm(a0[1]), ga = tanh_f(a0[2]), oa = sigm(a0[3]);
        c_a = fa * c_a + ia * ga;
        float hva = oa * tanh_f(c_a);
        float ib = sigm(a1[0]), fb = sigm(a1[1]), gb = tanh_f(a1[2]), ob = sigm(a1[3]);
        c_b = fb * c_b + ib * gb;
        float hvb = ob * tanh_f(c_b);
        bf16* hw = h0buf + (p & 1) * HBUF;
        hw[m * HDIM + ju]        = __float2bfloat16(hva);
        hw[(m + 16) * HDIM + ju] = __float2bfloat16(hvb);
      }
    } else {
      if (p >= 1) {
        // h1[p-1] = cell1(h0[p-1], h1[p-2])
        f32x4 a0 = bias, a1 = bias;
        const bf16* h0t = h0buf + ((p - 1) & 1) * HBUF;    // h0[p-1]
        const bf16* ha  = h0t + m * HDIM + q8;
        const bf16* hb  = h0t + (m + 16) * HDIM + q8;
#pragma unroll
        for (int kc = 0; kc < 16; kc++) {
          short8 b0 = *(const short8*)(const void*)(ha + kc * 32);
          short8 b1 = *(const short8*)(const void*)(hb + kc * 32);
          a0 = __builtin_amdgcn_mfma_f32_16x16x32_bf16(A[kc], b0, a0, 0, 0, 0);
          a1 = __builtin_amdgcn_mfma_f32_16x16x32_bf16(A[kc], b1, a1, 0, 0, 0);
        }
        if (p >= 2) {
          const bf16* h1p = h1buf + (p & 1) * HBUF;        // h1[p-2]
          const bf16* ha1 = h1p + m * HDIM + q8;
          const bf16* hb1 = h1p + (m + 16) * HDIM + q8;
#pragma unroll
          for (int kc = 0; kc < 16; kc++) {
            short8 b0 = *(const short8*)(const void*)(ha1 + kc * 32);
            short8 b1 = *(const short8*)(const void*)(hb1 + kc * 32);
            a0 = __builtin_amdgcn_mfma_f32_16x16x32_bf16(A[16 + kc], b0, a0, 0, 0, 0);
            a1 = __builtin_amdgcn_mfma_f32_16x16x32_bf16(A[16 + kc], b1, a1, 0, 0, 0);
          }
        }
        float ia = sigm(a0[0]), fa = sigm(a0[1]), ga = tanh_f(a0[2]), oa = sigm(a0[3]);
        c_a = fa * c_a + ia * ga;
        float hva = oa * tanh_f(c_a);
        float ib = sigm(a1[0]), fb = sigm(a1[1]), gb = tanh_f(a1[2]), ob = sigm(a1[3]);
        c_b = fb * c_b + ib * gb;
        float hvb = ob * tanh_f(c_b);
        bf16* hw = h1buf + ((p - 1) & 1) * HBUF;
        hw[m * HDIM + ju]        = __float2bfloat16(hva);
        hw[(m + 16) * HDIM + ju] = __float2bfloat16(hvb);
      }
    }
    gbar(cnt, (unsigned)(NBLK * (p + 1)));
  }

  // ---- FC epilogue: out[32,256] = h1[T-1] @ fcw^T + fcb ; blocks 0..15, wave 0 ----
  if (blockIdx.x < 16 && w == 0) {
    const int obase = blockIdx.x * 16;
    f32x4 a0, a1;
#pragma unroll
    for (int r = 0; r < 4; r++) {
      float bb = fcb[obase + 4 * q + r];
      a0[r] = bb;
      a1[r] = bb;
    }
    const bf16* h1l = h1buf + ((T_STEPS - 1) & 1) * HBUF;  // h1[2047]
    const float* Ar = fcw + (size_t)(obase + m) * HDIM + q8;
    const bf16* ha  = h1l + m * HDIM + q8;
    const bf16* hb  = h1l + (m + 16) * HDIM + q8;
#pragma unroll
    for (int kc = 0; kc < 16; kc++) {
      short8 af = cvt8(Ar + kc * 32);
      short8 b0 = *(const short8*)(const void*)(ha + kc * 32);
      short8 b1 = *(const short8*)(const void*)(hb + kc * 32);
      a0 = __builtin_amdgcn_mfma_f32_16x16x32_bf16(af, b0, a0, 0, 0, 0);
      a1 = __builtin_amdgcn_mfma_f32_16x16x32_bf16(af, b1, a1, 0, 0, 0);
    }
#pragma unroll
    for (int r = 0; r < 4; r++) {
      out[m * 256 + obase + 4 * q + r]        = a0[r];
      out[(m + 16) * 256 + obase + 4 * q + r] = a1[r];
    }
  }
}

extern "C" void kernel_launch(void* const* d_in, const int* in_sizes, int n_in,
                              void* d_out, int out_size, void* d_ws, size_t ws_size,
                              hipStream_t stream) {
  const float* x    = (const float*)d_in[0];
  const float* Wih0 = (const float*)d_in[1];
  const float* Whh0 = (const float*)d_in[2];
  const float* bih0 = (const float*)d_in[3];
  const float* bhh0 = (const float*)d_in[4];
  const float* Wih1 = (const float*)d_in[5];
  const float* Whh1 = (const float*)d_in[6];
  const float* bih1 = (const float*)d_in[7];
  const float* bhh1 = (const float*)d_in[8];
  const float* fcw  = (const float*)d_in[9];
  const float* fcb  = (const float*)d_in[10];

  // ws layout: [0,1024) barrier counter; then h0 double-buffer (64KB); then h1 (64KB)
  unsigned* cnt = (unsigned*)d_ws;
  bf16* h0buf = (bf16*)((char*)d_ws + 1024);
  bf16* h1buf = (bf16*)((char*)d_ws + 1024 + 2 * HBUF * sizeof(bf16));

  hipMemsetAsync(d_ws, 0, 1024, stream);   // zero barrier counter (ws is poisoned 0xAA)

  hipLaunchKernelGGL(lstm_persistent, dim3(NBLK), dim3(256), 0, stream,
                     x, Wih0, Whh0, bih0, bhh0, Wih1, Whh1, bih1, bhh1, fcw, fcb,
                     (float*)d_out, cnt, h0buf, h1buf);
}

// Round 3
// 27580.576 us; speedup vs baseline: 1.1529x; 1.1529x over previous
//
#include <hip/hip_runtime.h>
#include <hip/hip_bf16.h>

typedef __hip_bfloat16 bf16;
typedef unsigned long long u64;
using short8 = __attribute__((ext_vector_type(8))) short;   // 8 bf16 MFMA A/B frag
using f32x4  = __attribute__((ext_vector_type(4))) float;   // MFMA C/D frag

#define T_STEPS 2048
#define IDIM    256
#define HDIM    512
#define NB0     32
#define NBLK    64
#define HBUF    (32 * 512)        // one h buffer: 32 x 512 bf16
#define LROW    520               // LDS row stride (+8 pad -> 2-way-free banks)

__device__ __forceinline__ float sigm(float x) { return 1.0f / (1.0f + __expf(-x)); }
__device__ __forceinline__ float tanh_f(float x) {
  x = fminf(fmaxf(x, -15.f), 15.f);
  float e = __expf(2.f * x);
  return (e - 1.f) / (e + 1.f);
}
__device__ __forceinline__ short bfbits(float f) {
  bf16 b = __float2bfloat16(f); short s; __builtin_memcpy(&s, &b, 2); return s;
}
__device__ __forceinline__ short8 cvt8(const float* __restrict__ p) {
  float4 lo = *(const float4*)(const void*)p;
  float4 hi = *(const float4*)(const void*)(p + 4);
  short8 r;
  r[0] = bfbits(lo.x); r[1] = bfbits(lo.y); r[2] = bfbits(lo.z); r[3] = bfbits(lo.w);
  r[4] = bfbits(hi.x); r[5] = bfbits(hi.y); r[6] = bfbits(hi.z); r[7] = bfbits(hi.w);
  return r;
}

// LLC-coherent (cache-bypassing) 8B load/store: agent-scope relaxed atomics.
__device__ __forceinline__ u64 ldg8(const void* p) {
  return __hip_atomic_load((const u64*)p, __ATOMIC_RELAXED, __HIP_MEMORY_SCOPE_AGENT);
}
__device__ __forceinline__ void stg8(void* p, u64 v) {
  __hip_atomic_store((u64*)p, v, __ATOMIC_RELAXED, __HIP_MEMORY_SCOPE_AGENT);
}
__device__ __forceinline__ short8 ld16(const bf16* p) {
  union { u64 q[2]; short8 s; } u;
  u.q[0] = ldg8(p); u.q[1] = ldg8(p + 4);
  return u.s;
}

// Stage one 32x512 bf16 h-buffer (global, LLC) -> LDS [32][LROW]. 256 threads.
__device__ __forceinline__ void stage(const bf16* __restrict__ src, bf16* dst, int tid) {
  const u64* s = (const u64*)(const void*)src;
#pragma unroll
  for (int i = 0; i < 16; i++) {
    int chunk = tid + i * 256;          // 4096 8B-chunks total
    int row = chunk >> 7, c8 = chunk & 127;
    u64 v = __hip_atomic_load(s + row * 128 + c8, __ATOMIC_RELAXED, __HIP_MEMORY_SCOPE_AGENT);
    *(u64*)(void*)(dst + row * LROW + c8 * 4) = v;
  }
}

#define MFMA(a, b, c) __builtin_amdgcn_mfma_f32_16x16x32_bf16((a), (b), (c), 0, 0, 0)

__global__ void __launch_bounds__(256, 1) lstm_persistent(
    const float* __restrict__ x,
    const float* __restrict__ Wih0, const float* __restrict__ Whh0,
    const float* __restrict__ bih0, const float* __restrict__ bhh0,
    const float* __restrict__ Wih1, const float* __restrict__ Whh1,
    const float* __restrict__ bih1, const float* __restrict__ bhh1,
    const float* __restrict__ fcw, const float* __restrict__ fcb,
    float* __restrict__ out,
    unsigned* __restrict__ flags,
    bf16* __restrict__ h0buf, bf16* __restrict__ h1buf) {
  __shared__ __align__(16) bf16 lds_h0[32 * LROW];
  __shared__ __align__(16) bf16 lds_h1[32 * LROW];
  __shared__ __align__(16) bf16 hpack[32 * 16];

  const int tid  = threadIdx.x;
  const int w    = tid >> 6, lane = tid & 63;
  const int q    = lane >> 4, m = lane & 15, q8 = q * 8;
  const bool l0  = (blockIdx.x < NB0);
  const int blk  = l0 ? (int)blockIdx.x : (int)blockIdx.x - NB0;
  const int jb   = blk * 16 + w * 4;
  const int unit = jb + (m >> 2), gate = m & 3;
  const int wrow = gate * HDIM + unit;
  const int ju   = jb + q;

  // ---- Preload weights (f32 -> bf16 A-frags) into VGPRs ----
  short8 A[32];
  f32x4 bias;
  if (l0) {
#pragma unroll
    for (int kc = 0; kc < 8; kc++)  A[kc]      = cvt8(Wih0 + wrow * IDIM + kc * 32 + q8);
#pragma unroll
    for (int kc = 0; kc < 16; kc++) A[8 + kc]  = cvt8(Whh0 + wrow * HDIM + kc * 32 + q8);
#pragma unroll
    for (int r = 0; r < 4; r++)
      bias[r] = bih0[r * HDIM + ju] + bhh0[r * HDIM + ju];
  } else {
#pragma unroll
    for (int kc = 0; kc < 16; kc++) A[kc]      = cvt8(Wih1 + wrow * HDIM + kc * 32 + q8);
#pragma unroll
    for (int kc = 0; kc < 16; kc++) A[16 + kc] = cvt8(Whh1 + wrow * HDIM + kc * 32 + q8);
#pragma unroll
    for (int r = 0; r < 4; r++)
      bias[r] = bih1[r * HDIM + ju] + bhh1[r * HDIM + ju];
  }

  float c_a = 0.f, c_b = 0.f;
  f32x4 an0, an1;          // pipelined xg (layer 0 only)
  if (l0) {
    an0 = bias; an1 = bias;
    const float* xa = x + (size_t)m * (T_STEPS * IDIM) + q8;
    const float* xb = xa + (size_t)16 * (T_STEPS * IDIM);
#pragma unroll
    for (int kc = 0; kc < 8; kc++) {
      an0 = MFMA(A[kc], cvt8(xa + kc * 32), an0);
      an1 = MFMA(A[kc], cvt8(xb + kc * 32), an1);
    }
  }

  for (int p = 0; p <= T_STEPS; ++p) {
    if (l0) {
      if (p < T_STEPS) {
        f32x4 a0 = an0, a1 = an1;                    // bias + Wih0 x[p]
        if (p > 0) {
#pragma unroll
          for (int kc = 0; kc < 16; kc++) {
            short8 b0 = *(const short8*)(const void*)(lds_h0 + m * LROW + kc * 32 + q8);
            short8 b1 = *(const short8*)(const void*)(lds_h0 + (m + 16) * LROW + kc * 32 + q8);
            a0 = MFMA(A[8 + kc], b0, a0);
            a1 = MFMA(A[8 + kc], b1, a1);
          }
        }
        float ia = sigm(a0[0]), fa = sigm(a0[1]), ga = tanh_f(a0[2]), oa = sigm(a0[3]);
        c_a = fa * c_a + ia * ga;
        float hva = oa * tanh_f(c_a);
        float ib = sigm(a1[0]), fb = sigm(a1[1]), gb = tanh_f(a1[2]), ob = sigm(a1[3]);
        c_b = fb * c_b + ib * gb;
        float hvb = ob * tanh_f(c_b);
        hpack[m * 16 + (w * 4 + q)]        = __float2bfloat16(hva);
        hpack[(m + 16) * 16 + (w * 4 + q)] = __float2bfloat16(hvb);
        __syncthreads();
        if (w < 2) {                                  // coalesced packed h0 store
          int batch = w * 16 + (lane >> 2), ch = lane & 3;
          u64 v = *(const u64*)(const void*)(hpack + batch * 16 + ch * 4);
          stg8(h0buf + (p & 1) * HBUF + batch * HDIM + blk * 16 + ch * 4, v);
        }
        if (p + 1 < T_STEPS) {                        // pipeline xg[p+1] (off critical path)
          an0 = bias; an1 = bias;
          const float* xa = x + (size_t)m * (T_STEPS * IDIM) + (size_t)(p + 1) * IDIM + q8;
          const float* xb = xa + (size_t)16 * (T_STEPS * IDIM);
#pragma unroll
          for (int kc = 0; kc < 8; kc++) {
            an0 = MFMA(A[kc], cvt8(xa + kc * 32), an0);
            an1 = MFMA(A[kc], cvt8(xb + kc * 32), an1);
          }
        }
      }
    } else {
      if (p >= 1) {                                   // h1[p-1] = cell1(h0[p-1], h1[p-2])
        f32x4 a0 = bias, a1 = bias;
#pragma unroll
        for (int kc = 0; kc < 16; kc++) {
          short8 b0 = *(const short8*)(const void*)(lds_h0 + m * LROW + kc * 32 + q8);
          short8 b1 = *(const short8*)(const void*)(lds_h0 + (m + 16) * LROW + kc * 32 + q8);
          a0 = MFMA(A[kc], b0, a0);
          a1 = MFMA(A[kc], b1, a1);
        }
        if (p >= 2) {
#pragma unroll
          for (int kc = 0; kc < 16; kc++) {
            short8 b0 = *(const short8*)(const void*)(lds_h1 + m * LROW + kc * 32 + q8);
            short8 b1 = *(const short8*)(const void*)(lds_h1 + (m + 16) * LROW + kc * 32 + q8);
            a0 = MFMA(A[16 + kc], b0, a0);
            a1 = MFMA(A[16 + kc], b1, a1);
          }
        }
        float ia = sigm(a0[0]), fa = sigm(a0[1]), ga = tanh_f(a0[2]), oa = sigm(a0[3]);
        c_a = fa * c_a + ia * ga;
        float hva = oa * tanh_f(c_a);
        float ib = sigm(a1[0]), fb = sigm(a1[1]), gb = tanh_f(a1[2]), ob = sigm(a1[3]);
        c_b = fb * c_b + ib * gb;
        float hvb = ob * tanh_f(c_b);
        hpack[m * 16 + (w * 4 + q)]        = __float2bfloat16(hva);
        hpack[(m + 16) * 16 + (w * 4 + q)] = __float2bfloat16(hvb);
        __syncthreads();
        if (w < 2) {
          int batch = w * 16 + (lane >> 2), ch = lane & 3;
          u64 v = *(const u64*)(const void*)(hpack + batch * 16 + ch * 4);
          stg8(h1buf + ((p - 1) & 1) * HBUF + batch * HDIM + blk * 16 + ch * 4, v);
        }
      }
    }

    // ---- fence-free flag barrier: arrive(p+1), wait all >= p+1 ----
    asm volatile("s_waitcnt vmcnt(0)" ::: "memory");   // drain sc1 stores to LLC
    __syncthreads();
    if (w == 0) {
      if (lane == 0)
        __hip_atomic_store(flags + (unsigned)blockIdx.x * 4, (unsigned)(p + 1),
                           __ATOMIC_RELAXED, __HIP_MEMORY_SCOPE_AGENT);
      unsigned v;
      do {
        v = __hip_atomic_load(flags + lane * 4, __ATOMIC_RELAXED, __HIP_MEMORY_SCOPE_AGENT);
      } while (!__all((int)(v > (unsigned)p)));
    }
    __syncthreads();

    // ---- stage next phase's h vectors into LDS ----
    if (p < T_STEPS) {
      if (l0) {
        if (p + 1 < T_STEPS) { stage(h0buf + (p & 1) * HBUF, lds_h0, tid); __syncthreads(); }
      } else {
        stage(h0buf + (p & 1) * HBUF, lds_h0, tid);                 // h0[p]
        if (p >= 1) stage(h1buf + ((p - 1) & 1) * HBUF, lds_h1, tid); // h1[p-1]
        __syncthreads();
      }
    }
  }

  // ---- FC epilogue: out[32,256] = h1[T-1] @ fcw^T + fcb ; blocks 0..15, wave 0 ----
  if (blockIdx.x < 16 && w == 0) {
    const int obase = blockIdx.x * 16;
    f32x4 a0, a1;
#pragma unroll
    for (int r = 0; r < 4; r++) {
      float bb = fcb[obase + 4 * q + r];
      a0[r] = bb; a1[r] = bb;
    }
    const bf16* h1l = h1buf + ((T_STEPS - 1) & 1) * HBUF;
    const float* Ar = fcw + (size_t)(obase + m) * HDIM + q8;
#pragma unroll
    for (int kc = 0; kc < 16; kc++) {
      short8 af = cvt8(Ar + kc * 32);
      short8 b0 = ld16(h1l + m * HDIM + kc * 32 + q8);
      short8 b1 = ld16(h1l + (m + 16) * HDIM + kc * 32 + q8);
      a0 = MFMA(af, b0, a0);
      a1 = MFMA(af, b1, a1);
    }
#pragma unroll
    for (int r = 0; r < 4; r++) {
      out[m * 256 + obase + 4 * q + r]        = a0[r];
      out[(m + 16) * 256 + obase + 4 * q + r] = a1[r];
    }
  }
}

extern "C" void kernel_launch(void* const* d_in, const int* in_sizes, int n_in,
                              void* d_out, int out_size, void* d_ws, size_t ws_size,
                              hipStream_t stream) {
  const float* x    = (const float*)d_in[0];
  const float* Wih0 = (const float*)d_in[1];
  const float* Whh0 = (const float*)d_in[2];
  const float* bih0 = (const float*)d_in[3];
  const float* bhh0 = (const float*)d_in[4];
  const float* Wih1 = (const float*)d_in[5];
  const float* Whh1 = (const float*)d_in[6];
  const float* bih1 = (const float*)d_in[7];
  const float* bhh1 = (const float*)d_in[8];
  const float* fcw  = (const float*)d_in[9];
  const float* fcb  = (const float*)d_in[10];

  // ws layout: [0,4096) flag array (64 x 16B-strided uints); then h0/h1 double buffers
  unsigned* flags = (unsigned*)d_ws;
  bf16* h0buf = (bf16*)((char*)d_ws + 4096);
  bf16* h1buf = (bf16*)((char*)d_ws + 4096 + 2 * HBUF * sizeof(bf16));

  hipMemsetAsync(d_ws, 0, 4096, stream);   // zero flags (ws is poisoned 0xAA)

  hipLaunchKernelGGL(lstm_persistent, dim3(NBLK), dim3(256), 0, stream,
                     x, Wih0, Whh0, bih0, bhh0, Wih1, Whh1, bih1, bhh1, fcw, fcb,
                     (float*)d_out, flags, h0buf, h1buf);
}

// Round 4
// 26538.513 us; speedup vs baseline: 1.1982x; 1.0393x over previous
//
#include <hip/hip_runtime.h>
#include <hip/hip_bf16.h>

typedef __hip_bfloat16 bf16;
typedef unsigned long long u64;
typedef unsigned short u16;
using short8 = __attribute__((ext_vector_type(8))) short;   // 8 bf16 MFMA A/B frag
using f32x4  = __attribute__((ext_vector_type(4))) float;   // MFMA C/D frag

#define T_STEPS 2048
#define IDIM    256
#define HDIM    512
#define NB0     32
#define NBLK    64
#define HBUF    (32 * 512)        // one h buffer: 32 x 512 bf16
#define LROW    528               // LDS row stride elems: 1056 B = 264 dw == 8 mod 32 (conflict-floor)

__device__ __forceinline__ float sigm(float x) { return 1.0f / (1.0f + __expf(-x)); }
__device__ __forceinline__ float tanh_f(float x) {
  x = fminf(fmaxf(x, -15.f), 15.f);
  float e = __expf(2.f * x);
  return (e - 1.f) / (e + 1.f);
}
__device__ __forceinline__ short bfbits(float f) {
  bf16 b = __float2bfloat16(f); short s; __builtin_memcpy(&s, &b, 2); return s;
}
__device__ __forceinline__ short8 cvt8(const float* __restrict__ p) {
  float4 lo = *(const float4*)(const void*)p;
  float4 hi = *(const float4*)(const void*)(p + 4);
  short8 r;
  r[0] = bfbits(lo.x); r[1] = bfbits(lo.y); r[2] = bfbits(lo.z); r[3] = bfbits(lo.w);
  r[4] = bfbits(hi.x); r[5] = bfbits(hi.y); r[6] = bfbits(hi.z); r[7] = bfbits(hi.w);
  return r;
}

// LLC-coherent (L1/L2-bypassing) accesses: agent-scope relaxed atomics.
__device__ __forceinline__ u64 ldg8(const void* p) {
  return __hip_atomic_load((const u64*)p, __ATOMIC_RELAXED, __HIP_MEMORY_SCOPE_AGENT);
}
__device__ __forceinline__ unsigned ldg4(const unsigned* p) {
  return __hip_atomic_load(p, __ATOMIC_RELAXED, __HIP_MEMORY_SCOPE_AGENT);
}
__device__ __forceinline__ void stg4(unsigned* p, unsigned v) {
  __hip_atomic_store(p, v, __ATOMIC_RELAXED, __HIP_MEMORY_SCOPE_AGENT);
}
__device__ __forceinline__ void stg2(u16* p, u16 v) {
  __hip_atomic_store(p, v, __ATOMIC_RELAXED, __HIP_MEMORY_SCOPE_AGENT);
}
__device__ __forceinline__ short8 ld16(const bf16* p) {
  union { u64 q[2]; short8 s; } u;
  u.q[0] = ldg8(p); u.q[1] = ldg8(p + 4);
  return u.s;
}

// Stage one 32x512 bf16 h-buffer (LLC) -> LDS [32][LROW]. 256 threads, 16x8B each.
__device__ __forceinline__ void stage(const bf16* __restrict__ src, bf16* dst, int tid) {
  const u64* s = (const u64*)(const void*)src;
#pragma unroll
  for (int i = 0; i < 16; i++) {
    int chunk = tid + i * 256;          // 4096 8B-chunks
    int row = chunk >> 7, c8 = chunk & 127;
    u64 v = ldg8(s + row * 128 + c8);
    *(u64*)(void*)(dst + row * LROW + c8 * 4) = v;
  }
}

#define MFMA(a, b, c) __builtin_amdgcn_mfma_f32_16x16x32_bf16((a), (b), (c), 0, 0, 0)

__global__ void __launch_bounds__(256, 1) lstm_persistent(
    const float* __restrict__ x,
    const float* __restrict__ Wih0, const float* __restrict__ Whh0,
    const float* __restrict__ bih0, const float* __restrict__ bhh0,
    const float* __restrict__ Wih1, const float* __restrict__ Whh1,
    const float* __restrict__ bih1, const float* __restrict__ bhh1,
    const float* __restrict__ fcw, const float* __restrict__ fcb,
    float* __restrict__ out,
    unsigned* __restrict__ arr,     // 64 x 128B arrival lines
    unsigned* __restrict__ ep,      // 64 x 128B epoch broadcast lines
    bf16* __restrict__ h0buf, bf16* __restrict__ h1buf) {
  __shared__ __align__(16) bf16 lds_h0[32 * LROW];
  __shared__ __align__(16) bf16 lds_h1[32 * LROW];

  const int tid  = threadIdx.x;
  const int w    = tid >> 6, lane = tid & 63;
  const int q    = lane >> 4, m = lane & 15, q8 = q * 8;
  const bool l0  = (blockIdx.x < NB0);
  const int blk  = l0 ? (int)blockIdx.x : (int)blockIdx.x - NB0;
  const int jb   = blk * 16 + w * 4;
  const int unit = jb + (m >> 2), gate = m & 3;
  const int wrow = gate * HDIM + unit;
  const int ju   = jb + q;

  // ---- Preload weights (f32 -> bf16 A-frags) into VGPRs ----
  short8 A[32];
  f32x4 bias;
  if (l0) {
#pragma unroll
    for (int kc = 0; kc < 8; kc++)  A[kc]      = cvt8(Wih0 + wrow * IDIM + kc * 32 + q8);
#pragma unroll
    for (int kc = 0; kc < 16; kc++) A[8 + kc]  = cvt8(Whh0 + wrow * HDIM + kc * 32 + q8);
#pragma unroll
    for (int r = 0; r < 4; r++)
      bias[r] = bih0[r * HDIM + ju] + bhh0[r * HDIM + ju];
  } else {
#pragma unroll
    for (int kc = 0; kc < 16; kc++) A[kc]      = cvt8(Wih1 + wrow * HDIM + kc * 32 + q8);
#pragma unroll
    for (int kc = 0; kc < 16; kc++) A[16 + kc] = cvt8(Whh1 + wrow * HDIM + kc * 32 + q8);
#pragma unroll
    for (int r = 0; r < 4; r++)
      bias[r] = bih1[r * HDIM + ju] + bhh1[r * HDIM + ju];
  }

  float c_a = 0.f, c_b = 0.f;
  f32x4 an0, an1;                  // pipelined xg (layer 0 only)
  if (l0) {
    an0 = bias; an1 = bias;
    const float* xa = x + (size_t)m * (T_STEPS * IDIM) + q8;
    const float* xb = xa + (size_t)16 * (T_STEPS * IDIM);
#pragma unroll
    for (int kc = 0; kc < 8; kc++) {
      an0 = MFMA(A[kc], cvt8(xa + kc * 32), an0);
      an1 = MFMA(A[kc], cvt8(xb + kc * 32), an1);
    }
  }

  for (int p = 0; p <= T_STEPS; ++p) {
    // ================= compute + coherent scattered h store =================
    if (l0) {
      if (p < T_STEPS) {
        f32x4 a0 = an0, a1 = an1;                    // bias + Wih0 x[p]
        if (p > 0) {
#pragma unroll
          for (int kc = 0; kc < 16; kc++) {
            short8 b0 = *(const short8*)(const void*)(lds_h0 + m * LROW + kc * 32 + q8);
            short8 b1 = *(const short8*)(const void*)(lds_h0 + (m + 16) * LROW + kc * 32 + q8);
            a0 = MFMA(A[8 + kc], b0, a0);
            a1 = MFMA(A[8 + kc], b1, a1);
          }
        }
        float ia = sigm(a0[0]), fa = sigm(a0[1]), ga = tanh_f(a0[2]), oa = sigm(a0[3]);
        c_a = fa * c_a + ia * ga;
        float ib = sigm(a1[0]), fb = sigm(a1[1]), gb = tanh_f(a1[2]), ob = sigm(a1[3]);
        c_b = fb * c_b + ib * gb;
        u16* hw = (u16*)(h0buf + (p & 1) * HBUF);
        stg2(hw + m * HDIM + ju,        (u16)bfbits(oa * tanh_f(c_a)));
        stg2(hw + (m + 16) * HDIM + ju, (u16)bfbits(ob * tanh_f(c_b)));
      }
    } else {
      if (p >= 1) {                                   // h1[p-1] = cell1(h0[p-1], h1[p-2])
        f32x4 a0 = bias, a1 = bias;
#pragma unroll
        for (int kc = 0; kc < 16; kc++) {
          short8 b0 = *(const short8*)(const void*)(lds_h0 + m * LROW + kc * 32 + q8);
          short8 b1 = *(const short8*)(const void*)(lds_h0 + (m + 16) * LROW + kc * 32 + q8);
          a0 = MFMA(A[kc], b0, a0);
          a1 = MFMA(A[kc], b1, a1);
        }
        if (p >= 2) {
#pragma unroll
          for (int kc = 0; kc < 16; kc++) {
            short8 b0 = *(const short8*)(const void*)(lds_h1 + m * LROW + kc * 32 + q8);
            short8 b1 = *(const short8*)(const void*)(lds_h1 + (m + 16) * LROW + kc * 32 + q8);
            a0 = MFMA(A[16 + kc], b0, a0);
            a1 = MFMA(A[16 + kc], b1, a1);
          }
        }
        float ia = sigm(a0[0]), fa = sigm(a0[1]), ga = tanh_f(a0[2]), oa = sigm(a0[3]);
        c_a = fa * c_a + ia * ga;
        float ib = sigm(a1[0]), fb = sigm(a1[1]), gb = tanh_f(a1[2]), ob = sigm(a1[3]);
        c_b = fb * c_b + ib * gb;
        u16* hw = (u16*)(h1buf + ((p - 1) & 1) * HBUF);
        stg2(hw + m * HDIM + ju,        (u16)bfbits(oa * tanh_f(c_a)));
        stg2(hw + (m + 16) * HDIM + ju, (u16)bfbits(ob * tanh_f(c_b)));
      }
    }

    // ================= tree barrier: drain, arrive, (master), poll own line =================
    asm volatile("s_waitcnt vmcnt(0)" ::: "memory");   // data stores committed at LLC
    __syncthreads();                                   // all 4 waves' data drained
    if (w == 2 && lane == 0)
      stg4(arr + (unsigned)blockIdx.x * 32, (unsigned)(p + 1));   // arrival (own 128B line)

    // overlap poll-wait: prefetch xg[p+1] (layer 0; plain cached loads, read-only x)
    if (l0 && p + 1 < T_STEPS) {
      an0 = bias; an1 = bias;
      const float* xa = x + (size_t)m * (T_STEPS * IDIM) + (size_t)(p + 1) * IDIM + q8;
      const float* xb = xa + (size_t)16 * (T_STEPS * IDIM);
#pragma unroll
      for (int kc = 0; kc < 8; kc++) {
        an0 = MFMA(A[kc], cvt8(xa + kc * 32), an0);
        an1 = MFMA(A[kc], cvt8(xb + kc * 32), an1);
      }
    }

    if (blockIdx.x == 0 && w == 3) {                   // master: gather 64 arrivals, broadcast
      unsigned v;
      do { v = ldg4(arr + lane * 32); } while (!__all((int)(v > (unsigned)p)));
      stg4(ep + lane * 32, (unsigned)(p + 1));         // 64-line broadcast, one instruction
    }
    {
      unsigned v;                                       // every wave polls its block's own line
      do { v = ldg4(ep + (unsigned)blockIdx.x * 32); } while (v <= (unsigned)p);
    }

    // ================= stage next phase's h into LDS =================
    if (p < T_STEPS) {
      if (l0) {
        if (p + 1 < T_STEPS) stage(h0buf + (p & 1) * HBUF, lds_h0, tid);
      } else {
        stage(h0buf + (p & 1) * HBUF, lds_h0, tid);                   // h0[p]
        if (p >= 1) stage(h1buf + ((p - 1) & 1) * HBUF, lds_h1, tid); // h1[p-1]
      }
      __syncthreads();
    }
  }

  // ---- FC epilogue: out[32,256] = h1[T-1] @ fcw^T + fcb ; blocks 0..15, wave 0 ----
  if (blockIdx.x < 16 && w == 0) {
    const int obase = blockIdx.x * 16;
    f32x4 a0, a1;
#pragma unroll
    for (int r = 0; r < 4; r++) {
      float bb = fcb[obase + 4 * q + r];
      a0[r] = bb; a1[r] = bb;
    }
    const bf16* h1l = h1buf + ((T_STEPS - 1) & 1) * HBUF;
    const float* Ar = fcw + (size_t)(obase + m) * HDIM + q8;
#pragma unroll
    for (int kc = 0; kc < 16; kc++) {
      short8 af = cvt8(Ar + kc * 32);
      short8 b0 = ld16(h1l + m * HDIM + kc * 32 + q8);
      short8 b1 = ld16(h1l + (m + 16) * HDIM + kc * 32 + q8);
      a0 = MFMA(af, b0, a0);
      a1 = MFMA(af, b1, a1);
    }
#pragma unroll
    for (int r = 0; r < 4; r++) {
      out[m * 256 + obase + 4 * q + r]        = a0[r];
      out[(m + 16) * 256 + obase + 4 * q + r] = a1[r];
    }
  }
}

extern "C" void kernel_launch(void* const* d_in, const int* in_sizes, int n_in,
                              void* d_out, int out_size, void* d_ws, size_t ws_size,
                              hipStream_t stream) {
  const float* x    = (const float*)d_in[0];
  const float* Wih0 = (const float*)d_in[1];
  const float* Whh0 = (const float*)d_in[2];
  const float* bih0 = (const float*)d_in[3];
  const float* bhh0 = (const float*)d_in[4];
  const float* Wih1 = (const float*)d_in[5];
  const float* Whh1 = (const float*)d_in[6];
  const float* bih1 = (const float*)d_in[7];
  const float* bhh1 = (const float*)d_in[8];
  const float* fcw  = (const float*)d_in[9];
  const float* fcb  = (const float*)d_in[10];

  // ws: [0,8K) arrival lines; [8K,16K) epoch lines; then h0/h1 double buffers
  unsigned* arr = (unsigned*)d_ws;
  unsigned* ep  = (unsigned*)((char*)d_ws + 8192);
  bf16* h0buf = (bf16*)((char*)d_ws + 16384);
  bf16* h1buf = (bf16*)((char*)d_ws + 16384 + 2 * HBUF * sizeof(bf16));

  hipMemsetAsync(d_ws, 0, 16384, stream);   // zero barrier lines (ws poisoned 0xAA)

  hipLaunchKernelGGL(lstm_persistent, dim3(NBLK), dim3(256), 0, stream,
                     x, Wih0, Whh0, bih0, bhh0, Wih1, Whh1, bih1, bhh1, fcw, fcb,
                     (float*)d_out, arr, ep, h0buf, h1buf);
}

// Round 5
// 17155.579 us; speedup vs baseline: 1.8535x; 1.5469x over previous
//
#include <hip/hip_runtime.h>
#include <hip/hip_bf16.h>

typedef __hip_bfloat16 bf16;
typedef unsigned long long u64;
typedef unsigned int u32;
typedef unsigned short u16;
using short8 = __attribute__((ext_vector_type(8))) short;   // 8 bf16 MFMA A/B frag
using f32x4  = __attribute__((ext_vector_type(4))) float;   // MFMA C/D frag

#define T_STEPS 2048
#define IDIM    256
#define HDIM    512
#define NB0     32
#define NBLK    64
#define R0      8                 // h0 ring slots
#define HW      (32 * 512)        // u32 words per h buffer (value<<16 | epoch)
#define LROW    528               // LDS row stride (bf16 elems); 1056B == 8 dw mod 32

__device__ __forceinline__ float sigm(float x) { return 1.0f / (1.0f + __expf(-x)); }
__device__ __forceinline__ float tanh_f(float x) {
  x = fminf(fmaxf(x, -15.f), 15.f);
  float e = __expf(2.f * x);
  return (e - 1.f) / (e + 1.f);
}
__device__ __forceinline__ u16 bfbits(float f) {
  bf16 b = __float2bfloat16(f); u16 s; __builtin_memcpy(&s, &b, 2); return s;
}
__device__ __forceinline__ short8 cvt8(const float* __restrict__ p) {
  float4 lo = *(const float4*)(const void*)p;
  float4 hi = *(const float4*)(const void*)(p + 4);
  short8 r;
  r[0] = (short)bfbits(lo.x); r[1] = (short)bfbits(lo.y); r[2] = (short)bfbits(lo.z); r[3] = (short)bfbits(lo.w);
  r[4] = (short)bfbits(hi.x); r[5] = (short)bfbits(hi.y); r[6] = (short)bfbits(hi.z); r[7] = (short)bfbits(hi.w);
  return r;
}

// LLC-coherent (L1/L2-bypassing) accesses: agent-scope relaxed atomics.
__device__ __forceinline__ u64 ldg8(const u64* p) {
  return __hip_atomic_load(p, __ATOMIC_RELAXED, __HIP_MEMORY_SCOPE_AGENT);
}
__device__ __forceinline__ u32 ldg4(const u32* p) {
  return __hip_atomic_load(p, __ATOMIC_RELAXED, __HIP_MEMORY_SCOPE_AGENT);
}
__device__ __forceinline__ void stg4(u32* p, u32 v) {
  __hip_atomic_store(p, v, __ATOMIC_RELAXED, __HIP_MEMORY_SCOPE_AGENT);
}

// Write one validated u64 chunk (2 tagged words) into LDS as a packed bf16 pair.
__device__ __forceinline__ void ldsw(bf16* dst, int c, u64 v) {
  u32 lo = (u32)v, hi = (u32)(v >> 32);
  u32 packed = (lo >> 16) | (hi & 0xffff0000u);   // [val1|val0]
  *(u32*)(void*)(dst + (c >> 8) * LROW + (c & 255) * 2) = packed;
}

#define TAGMASK 0x0000ffff0000ffffULL

// Poll-stage one tagged 64KB h buffer -> LDS. 256 threads x 32 u64 chunks.
// The loads ARE the sync: re-issue (mask-parallel) any chunk whose epochs != tag.
__device__ __forceinline__ void stage1(const u32* __restrict__ src, bf16* dst, int tid, u32 tag) {
  const u64* s = (const u64*)(const void*)src;
  const u64 tt = ((u64)tag << 32) | tag;
  u64 v[32];
#pragma unroll
  for (int i = 0; i < 32; i++) v[i] = ldg8(s + tid + i * 256);
  unsigned bad = 0xffffffffu;
  while (bad) {
    unsigned nb = 0;
#pragma unroll
    for (int i = 0; i < 32; i++)
      if (bad & (1u << i)) {
        if ((v[i] & TAGMASK) != tt) { v[i] = ldg8(s + tid + i * 256); nb |= 1u << i; }
      }
    bad = nb;
  }
#pragma unroll
  for (int i = 0; i < 32; i++) ldsw(dst, tid + i * 256, v[i]);
}

// Poll-stage two tagged buffers concurrently (l1: h0 and h1).
__device__ __forceinline__ void stage2(const u32* __restrict__ s0p, bf16* d0, u32 tag0,
                                       const u32* __restrict__ s1p, bf16* d1, u32 tag1,
                                       int tid) {
  const u64* s0 = (const u64*)(const void*)s0p;
  const u64* s1 = (const u64*)(const void*)s1p;
  const u64 tt0 = ((u64)tag0 << 32) | tag0;
  const u64 tt1 = ((u64)tag1 << 32) | tag1;
  u64 v0[32], v1[32];
#pragma unroll
  for (int i = 0; i < 32; i++) v0[i] = ldg8(s0 + tid + i * 256);
#pragma unroll
  for (int i = 0; i < 32; i++) v1[i] = ldg8(s1 + tid + i * 256);
  unsigned bad0 = 0xffffffffu, bad1 = 0xffffffffu;
  while (bad0 | bad1) {
    unsigned nb0 = 0, nb1 = 0;
#pragma unroll
    for (int i = 0; i < 32; i++)
      if (bad0 & (1u << i)) {
        if ((v0[i] & TAGMASK) != tt0) { v0[i] = ldg8(s0 + tid + i * 256); nb0 |= 1u << i; }
      }
#pragma unroll
    for (int i = 0; i < 32; i++)
      if (bad1 & (1u << i)) {
        if ((v1[i] & TAGMASK) != tt1) { v1[i] = ldg8(s1 + tid + i * 256); nb1 |= 1u << i; }
      }
    bad0 = nb0; bad1 = nb1;
  }
#pragma unroll
  for (int i = 0; i < 32; i++) ldsw(d0, tid + i * 256, v0[i]);
#pragma unroll
  for (int i = 0; i < 32; i++) ldsw(d1, tid + i * 256, v1[i]);
}

__device__ __forceinline__ int wave_min_i(int v) {
#pragma unroll
  for (int off = 32; off > 0; off >>= 1) {
    int o = __shfl_xor(v, off, 64);
    v = v < o ? v : o;
  }
  return v;
}

#define MFMA(a, b, c) __builtin_amdgcn_mfma_f32_16x16x32_bf16((a), (b), (c), 0, 0, 0)

__global__ void __launch_bounds__(256, 1) lstm_persistent(
    const float* __restrict__ x,
    const float* __restrict__ Wih0, const float* __restrict__ Whh0,
    const float* __restrict__ bih0, const float* __restrict__ bhh0,
    const float* __restrict__ Wih1, const float* __restrict__ Whh1,
    const float* __restrict__ bih1, const float* __restrict__ bhh1,
    const float* __restrict__ fcw, const float* __restrict__ fcb,
    float* __restrict__ out,
    u32* __restrict__ prog,        // 32 x 128B l1 progress lines
    u32* __restrict__ h0ring,      // R0 x HW tagged words
    u32* __restrict__ h1ring) {    // 2  x HW tagged words
  __shared__ __align__(16) bf16 lds_h0[32 * LROW];
  __shared__ __align__(16) bf16 lds_h1[32 * LROW];

  const int tid  = threadIdx.x;
  const int w    = tid >> 6, lane = tid & 63;
  const int q    = lane >> 4, m = lane & 15, q8 = q * 8;
  const int bx   = (int)blockIdx.x;
  const bool l0  = (bx < NB0);
  const int blk  = l0 ? bx : bx - NB0;
  const int jb   = blk * 16 + w * 4;
  const int unit = jb + (m >> 2), gate = m & 3;
  const int wrow = gate * HDIM + unit;
  const int ju   = jb + q;

  // ---- Preload weights (f32 -> bf16 A-frags) into VGPRs ----
  short8 A[32];
  f32x4 bias;
  if (l0) {
#pragma unroll
    for (int kc = 0; kc < 8; kc++)  A[kc]      = cvt8(Wih0 + wrow * IDIM + kc * 32 + q8);
#pragma unroll
    for (int kc = 0; kc < 16; kc++) A[8 + kc]  = cvt8(Whh0 + wrow * HDIM + kc * 32 + q8);
#pragma unroll
    for (int r = 0; r < 4; r++)
      bias[r] = bih0[r * HDIM + ju] + bhh0[r * HDIM + ju];
  } else {
#pragma unroll
    for (int kc = 0; kc < 16; kc++) A[kc]      = cvt8(Wih1 + wrow * HDIM + kc * 32 + q8);
#pragma unroll
    for (int kc = 0; kc < 16; kc++) A[16 + kc] = cvt8(Whh1 + wrow * HDIM + kc * 32 + q8);
#pragma unroll
    for (int r = 0; r < 4; r++)
      bias[r] = bih1[r * HDIM + ju] + bhh1[r * HDIM + ju];
  }

  float c_a = 0.f, c_b = 0.f;

  if (l0) {
    // prefetch xg[0]
    f32x4 an0 = bias, an1 = bias;
    {
      const float* xa = x + (size_t)m * (T_STEPS * IDIM) + q8;
      const float* xb = xa + (size_t)16 * (T_STEPS * IDIM);
#pragma unroll
      for (int kc = 0; kc < 8; kc++) {
        an0 = MFMA(A[kc], cvt8(xa + kc * 32), an0);
        an1 = MFMA(A[kc], cvt8(xb + kc * 32), an1);
      }
    }
    int est = 0;   // cached min l1 progress
    for (int p = 0; p < T_STEPS; ++p) {
      if (p > 0) {
        stage1(h0ring + ((p - 1) & (R0 - 1)) * HW, lds_h0, tid, (u32)p);   // h0[p-1], tag p
        __syncthreads();
      }
      f32x4 a0 = an0, a1 = an1;                       // bias + Wih0 x[p]
      if (p > 0) {
#pragma unroll
        for (int kc = 0; kc < 16; kc++) {
          short8 b0 = *(const short8*)(const void*)(lds_h0 + m * LROW + kc * 32 + q8);
          short8 b1 = *(const short8*)(const void*)(lds_h0 + (m + 16) * LROW + kc * 32 + q8);
          a0 = MFMA(A[8 + kc], b0, a0);
          a1 = MFMA(A[8 + kc], b1, a1);
        }
      }
      float ia = sigm(a0[0]), fa = sigm(a0[1]), ga = tanh_f(a0[2]), oa = sigm(a0[3]);
      c_a = fa * c_a + ia * ga;
      float ib = sigm(a1[0]), fb = sigm(a1[1]), gb = tanh_f(a1[2]), ob = sigm(a1[3]);
      c_b = fb * c_b + ib * gb;
      u16 hb_a = bfbits(oa * tanh_f(c_a));
      u16 hb_b = bfbits(ob * tanh_f(c_b));

      // flow control: slot p%R0 currently holds h0[p-R0] (readers: l1 step p-R0 -> prog p-R0+1)
      if (p >= R0) {
        int needed = p - R0 + 1;
        if (est < needed) {
          int mn;
          do {
            u32 pr = ldg4(prog + (lane & 31) * 32);
            mn = wave_min_i((int)pr);
          } while (mn < needed);
          est = mn;
        }
      }
      u32 tag = (u32)(p + 1);
      u32* hw = h0ring + (p & (R0 - 1)) * HW;
      stg4(hw + m * HDIM + ju,        ((u32)hb_a << 16) | tag);
      stg4(hw + (m + 16) * HDIM + ju, ((u32)hb_b << 16) | tag);

      if (p + 1 < T_STEPS) {                          // prefetch xg[p+1]
        an0 = bias; an1 = bias;
        const float* xa = x + (size_t)m * (T_STEPS * IDIM) + (size_t)(p + 1) * IDIM + q8;
        const float* xb = xa + (size_t)16 * (T_STEPS * IDIM);
#pragma unroll
        for (int kc = 0; kc < 8; kc++) {
          an0 = MFMA(A[kc], cvt8(xa + kc * 32), an0);
          an1 = MFMA(A[kc], cvt8(xb + kc * 32), an1);
        }
      }
      __syncthreads();   // LDS reads done before next iteration's staging overwrites
    }

    // ---- FC epilogue: blocks 0..15 poll h1[T-1] tags directly ----
    if (bx < 16) {
      stage1(h1ring + ((T_STEPS - 1) & 1) * HW, lds_h0, tid, (u32)T_STEPS);
      __syncthreads();
      if (w == 0) {
        const int obase = bx * 16;
        f32x4 a0, a1;
#pragma unroll
        for (int r = 0; r < 4; r++) {
          float bb = fcb[obase + 4 * q + r];
          a0[r] = bb; a1[r] = bb;
        }
        const float* Ar = fcw + (size_t)(obase + m) * HDIM + q8;
#pragma unroll
        for (int kc = 0; kc < 16; kc++) {
          short8 af = cvt8(Ar + kc * 32);
          short8 b0 = *(const short8*)(const void*)(lds_h0 + m * LROW + kc * 32 + q8);
          short8 b1 = *(const short8*)(const void*)(lds_h0 + (m + 16) * LROW + kc * 32 + q8);
          a0 = MFMA(af, b0, a0);
          a1 = MFMA(af, b1, a1);
        }
#pragma unroll
        for (int r = 0; r < 4; r++) {
          out[m * 256 + obase + 4 * q + r]        = a0[r];
          out[(m + 16) * 256 + obase + 4 * q + r] = a1[r];
        }
      }
    }
  } else {
    // ---- layer 1: pure dataflow consumer/producer ----
    for (int p = 0; p < T_STEPS; ++p) {
      if (p == 0) {
        stage1(h0ring + 0 * HW, lds_h0, tid, 1u);                       // h0[0], tag 1
      } else {
        stage2(h0ring + (p & (R0 - 1)) * HW, lds_h0, (u32)(p + 1),      // h0[p]
               h1ring + ((p - 1) & 1) * HW,  lds_h1, (u32)p, tid);      // h1[p-1]
      }
      __syncthreads();
      if (tid == 0) stg4(prog + (bx - NB0) * 32, (u32)(p + 1));         // done reading h0[p]

      f32x4 a0 = bias, a1 = bias;
#pragma unroll
      for (int kc = 0; kc < 16; kc++) {
        short8 b0 = *(const short8*)(const void*)(lds_h0 + m * LROW + kc * 32 + q8);
        short8 b1 = *(const short8*)(const void*)(lds_h0 + (m + 16) * LROW + kc * 32 + q8);
        a0 = MFMA(A[kc], b0, a0);
        a1 = MFMA(A[kc], b1, a1);
      }
      if (p >= 1) {
#pragma unroll
        for (int kc = 0; kc < 16; kc++) {
          short8 b0 = *(const short8*)(const void*)(lds_h1 + m * LROW + kc * 32 + q8);
          short8 b1 = *(const short8*)(const void*)(lds_h1 + (m + 16) * LROW + kc * 32 + q8);
          a0 = MFMA(A[16 + kc], b0, a0);
          a1 = MFMA(A[16 + kc], b1, a1);
        }
      }
      float ia = sigm(a0[0]), fa = sigm(a0[1]), ga = tanh_f(a0[2]), oa = sigm(a0[3]);
      c_a = fa * c_a + ia * ga;
      float ib = sigm(a1[0]), fb = sigm(a1[1]), gb = tanh_f(a1[2]), ob = sigm(a1[3]);
      c_b = fb * c_b + ib * gb;
      u32 tag = (u32)(p + 1);
      u32* hw = h1ring + (p & 1) * HW;
      stg4(hw + m * HDIM + ju,        ((u32)bfbits(oa * tanh_f(c_a)) << 16) | tag);
      stg4(hw + (m + 16) * HDIM + ju, ((u32)bfbits(ob * tanh_f(c_b)) << 16) | tag);
      __syncthreads();   // LDS reads done before next iteration's staging overwrites
    }
  }
}

extern "C" void kernel_launch(void* const* d_in, const int* in_sizes, int n_in,
                              void* d_out, int out_size, void* d_ws, size_t ws_size,
                              hipStream_t stream) {
  const float* x    = (const float*)d_in[0];
  const float* Wih0 = (const float*)d_in[1];
  const float* Whh0 = (const float*)d_in[2];
  const float* bih0 = (const float*)d_in[3];
  const float* bhh0 = (const float*)d_in[4];
  const float* Wih1 = (const float*)d_in[5];
  const float* Whh1 = (const float*)d_in[6];
  const float* bih1 = (const float*)d_in[7];
  const float* bhh1 = (const float*)d_in[8];
  const float* fcw  = (const float*)d_in[9];
  const float* fcb  = (const float*)d_in[10];

  // ws: [0,4K) l1 progress lines (zeroed); [4K, 4K+512K) h0 ring; then 128K h1 ring.
  // Ring slots are NOT zeroed: 0xAA poison gives epoch fields 0xAAAA, which never
  // equals any tag in [1,2048] -> consumers just spin until real data lands.
  u32* prog   = (u32*)d_ws;
  u32* h0ring = (u32*)((char*)d_ws + 4096);
  u32* h1ring = (u32*)((char*)d_ws + 4096 + (size_t)R0 * HW * sizeof(u32));

  hipMemsetAsync(d_ws, 0, 4096, stream);   // progress counters start at 0

  hipLaunchKernelGGL(lstm_persistent, dim3(NBLK), dim3(256), 0, stream,
                     x, Wih0, Whh0, bih0, bhh0, Wih1, Whh1, bih1, bhh1, fcw, fcb,
                     (float*)d_out, prog, h0ring, h1ring);
}